// Round 1
// baseline (2812.318 us; speedup 1.0000x reference)
//
#include <hip/hip_runtime.h>

#define NN 100000
#define NE 200000
#define HH 32
#define NL 4
#define NGR 50
#define GOUT 100
#define NODE_IN 6

// ---------------- embed: h0 = relu(x @ w_emb + b_emb), partial BN stats ----------------
__global__ __launch_bounds__(256) void embed_kernel(
    const float* __restrict__ x, const float* __restrict__ w,
    const float* __restrict__ b, float* __restrict__ h0,
    float* __restrict__ stats)
{
    __shared__ float ls[64];  // [0:32) sum, [32:64) sumsq
    int tid = threadIdx.x;
    if (tid < 64) ls[tid] = 0.f;
    __syncthreads();
    int nid = blockIdx.x * 256 + tid;
    if (nid < NN) {
        float xv[NODE_IN];
        #pragma unroll
        for (int d = 0; d < NODE_IN; ++d) xv[d] = x[nid * NODE_IN + d];
        #pragma unroll
        for (int j = 0; j < HH; ++j) {
            float a = b[j];
            #pragma unroll
            for (int d = 0; d < NODE_IN; ++d) a = fmaf(xv[d], w[d * HH + j], a);
            a = fmaxf(a, 0.f);
            h0[nid * HH + j] = a;
            atomicAdd(&ls[j], a);
            atomicAdd(&ls[32 + j], a * a);
        }
    }
    __syncthreads();
    if (tid < 64) unsafeAtomicAdd(&stats[tid], ls[tid]);
}

// ---------------- degree ----------------
__global__ __launch_bounds__(256) void deg_kernel(const int* __restrict__ ei,
                                                  float* __restrict__ deg)
{
    int e = blockIdx.x * 256 + threadIdx.x;
    if (e >= NE) return;
    unsafeAtomicAdd(&deg[ei[NE + e]], 1.0f);
}

// ---------------- BN finalize: scale/shift per column ----------------
__global__ void bn_finalize(const float* __restrict__ stats,
                            const float* __restrict__ gamma,
                            const float* __restrict__ beta,
                            float* __restrict__ bnp)
{
    int j = threadIdx.x;
    if (j >= HH) return;
    const float invn = 1.0f / (float)NN;
    float mu  = stats[j] * invn;
    float var = stats[32 + j] * invn - mu * mu;
    float rs  = 1.0f / sqrtf(var + 1e-5f);
    float sc  = rs * gamma[j];
    bnp[j]      = sc;
    bnp[32 + j] = beta[j] - mu * sc;
}

// ---------------- BN apply (in place, float4) ----------------
__global__ __launch_bounds__(256) void bn_apply(float* __restrict__ h,
                                                const float* __restrict__ bnp)
{
    int idx = blockIdx.x * 256 + threadIdx.x;
    if (idx >= NN * HH / 4) return;
    float4 v = ((float4*)h)[idx];
    int j = (idx * 4) & 31;
    v.x = fmaf(v.x, bnp[j + 0], bnp[32 + j + 0]);
    v.y = fmaf(v.y, bnp[j + 1], bnp[32 + j + 1]);
    v.z = fmaf(v.z, bnp[j + 2], bnp[32 + j + 2]);
    v.w = fmaf(v.w, bnp[j + 3], bnp[32 + j + 3]);
    ((float4*)h)[idx] = v;
}

// ---------------- NNConv edge kernel: fused edge-MLP + h[src]·W + scatter ----------------
// msg[o] = sum_i h_src[i] * ( sum_k t[k]*w2[k,i*32+o] + b2[i*32+o] ),
// t = relu(ea @ w1 + b1).  Thread = edge; w2/w1 indices are wave-uniform
// (loop constants) -> scalar loads, broadcast into the FMA.
__global__ __launch_bounds__(256) void edge_kernel(
    const float* __restrict__ h, const int* __restrict__ ei,
    const float* __restrict__ ea, const float* __restrict__ w1,
    const float* __restrict__ b1, const float* __restrict__ w2,
    const float* __restrict__ b2, float* __restrict__ agg)
{
    int e = blockIdx.x * 256 + threadIdx.x;
    if (e >= NE) return;
    int src = ei[e];
    int dst = ei[NE + e];
    float eav[4];
    {
        float4 t4 = *(const float4*)(ea + e * 4);
        eav[0] = t4.x; eav[1] = t4.y; eav[2] = t4.z; eav[3] = t4.w;
    }
    float hv[HH];
    {
        const float4* hp = (const float4*)(h + src * HH);
        #pragma unroll
        for (int q = 0; q < 8; ++q) {
            float4 v = hp[q];
            hv[4*q+0] = v.x; hv[4*q+1] = v.y; hv[4*q+2] = v.z; hv[4*q+3] = v.w;
        }
    }
    float acc[HH];
    #pragma unroll
    for (int o = 0; o < HH; ++o) acc[o] = 0.f;
    // b2 contribution
    #pragma unroll
    for (int i = 0; i < HH; ++i) {
        float hi = hv[i];
        #pragma unroll
        for (int o = 0; o < HH; ++o) acc[o] = fmaf(hi, b2[i * HH + o], acc[o]);
    }
    // main contraction over k (edge-MLP hidden dim)
    for (int k = 0; k < 64; ++k) {
        float t = b1[k];
        #pragma unroll
        for (int j = 0; j < 4; ++j) t = fmaf(eav[j], w1[j * 64 + k], t);
        t = fmaxf(t, 0.f);
        const float* __restrict__ w2k = w2 + k * (HH * HH);
        #pragma unroll
        for (int i = 0; i < HH; ++i) {
            float z = t * hv[i];
            #pragma unroll
            for (int o = 0; o < HH; ++o) acc[o] = fmaf(z, w2k[i * HH + o], acc[o]);
        }
    }
    float* ap = agg + dst * HH;
    #pragma unroll
    for (int o = 0; o < HH; ++o) unsafeAtomicAdd(ap + o, acc[o]);
}

// ---------------- node update: h' = relu(agg*inv_deg + h@root + bias) ----------------
__global__ __launch_bounds__(256) void node_kernel(
    const float* __restrict__ h, const float* __restrict__ agg,
    const float* __restrict__ deg, const float* __restrict__ root,
    const float* __restrict__ bias, float* __restrict__ hout)
{
    int nid = blockIdx.x * 256 + threadIdx.x;
    if (nid >= NN) return;
    float hv[HH];
    {
        const float4* hp = (const float4*)(h + nid * HH);
        #pragma unroll
        for (int q = 0; q < 8; ++q) {
            float4 v = hp[q];
            hv[4*q+0] = v.x; hv[4*q+1] = v.y; hv[4*q+2] = v.z; hv[4*q+3] = v.w;
        }
    }
    float inv = 1.0f / fmaxf(deg[nid], 1.0f);
    float acc[HH];
    #pragma unroll
    for (int o = 0; o < HH; ++o) acc[o] = bias[o];
    #pragma unroll
    for (int i = 0; i < HH; ++i) {
        float hi = hv[i];
        #pragma unroll
        for (int o = 0; o < HH; ++o) acc[o] = fmaf(hi, root[i * HH + o], acc[o]);
    }
    const float4* av = (const float4*)(agg + nid * HH);
    #pragma unroll
    for (int q = 0; q < 8; ++q) {
        float4 a = av[q];
        float4 r;
        r.x = fmaxf(fmaf(a.x, inv, acc[4*q+0]), 0.f);
        r.y = fmaxf(fmaf(a.y, inv, acc[4*q+1]), 0.f);
        r.z = fmaxf(fmaf(a.z, inv, acc[4*q+2]), 0.f);
        r.w = fmaxf(fmaf(a.w, inv, acc[4*q+3]), 0.f);
        ((float4*)(hout + nid * HH))[q] = r;
    }
}

// ---------------- global mean pool (LDS pre-aggregation, all 50 graphs fit) ----------------
__global__ __launch_bounds__(256) void pool_kernel(
    const float* __restrict__ h, const int* __restrict__ batch,
    float* __restrict__ pool, float* __restrict__ cnt)
{
    __shared__ float lp[NGR * HH];
    __shared__ float lc[NGR];
    int tid = threadIdx.x;
    for (int i = tid; i < NGR * HH; i += 256) lp[i] = 0.f;
    for (int i = tid; i < NGR; i += 256) lc[i] = 0.f;
    __syncthreads();
    int nid = blockIdx.x * 256 + tid;
    if (nid < NN) {
        int g = batch[nid];
        atomicAdd(&lc[g], 1.0f);
        #pragma unroll
        for (int j = 0; j < HH; ++j) atomicAdd(&lp[g * HH + j], h[nid * HH + j]);
    }
    __syncthreads();
    for (int i = tid; i < NGR * HH; i += 256)
        if (lp[i] != 0.f) unsafeAtomicAdd(&pool[i], lp[i]);
    for (int i = tid; i < NGR; i += 256)
        if (lc[i] != 0.f) unsafeAtomicAdd(&cnt[i], lc[i]);
}

// ---------------- heads: blockIdx = head (0:wk, 1:uj, 2:zk) ----------------
__global__ __launch_bounds__(256) void heads_kernel(
    const float* __restrict__ pool, const float* __restrict__ cnt,
    const float* __restrict__ wkw1, const float* __restrict__ wkb1,
    const float* __restrict__ wkw2, const float* __restrict__ wkb2,
    const float* __restrict__ ujw1, const float* __restrict__ ujb1,
    const float* __restrict__ ujw2, const float* __restrict__ ujb2,
    const float* __restrict__ zkw1, const float* __restrict__ zkb1,
    const float* __restrict__ zkw2, const float* __restrict__ zkb2,
    float* __restrict__ out)
{
    __shared__ float hg[NGR * HH];
    __shared__ float hid[NGR * HH];
    int tid = threadIdx.x;
    int head = blockIdx.x;
    const float *w1, *b1, *w2, *b2;
    if (head == 0)      { w1 = wkw1; b1 = wkb1; w2 = wkw2; b2 = wkb2; }
    else if (head == 1) { w1 = ujw1; b1 = ujb1; w2 = ujw2; b2 = ujb2; }
    else                { w1 = zkw1; b1 = zkb1; w2 = zkw2; b2 = zkb2; }
    for (int i = tid; i < NGR * HH; i += 256) {
        int g = i >> 5;
        hg[i] = pool[i] / fmaxf(cnt[g], 1.0f);
    }
    __syncthreads();
    for (int i = tid; i < NGR * HH; i += 256) {
        int g = i >> 5, c = i & 31;
        float a = b1[c];
        for (int j = 0; j < HH; ++j) a = fmaf(hg[g * HH + j], w1[j * HH + c], a);
        hid[i] = fmaxf(a, 0.f);
    }
    __syncthreads();
    if (head == 0) {
        if (tid < NGR) {
            float a = b2[0];
            for (int c = 0; c < HH; ++c) a = fmaf(hid[tid * HH + c], w2[c], a);
            out[tid] = a;
        }
    } else {
        float* ob = out + NGR + (head - 1) * NGR * GOUT;
        for (int i = tid; i < NGR * GOUT; i += 256) {
            int g = i / GOUT, u = i % GOUT;
            float a = b2[u];
            for (int c = 0; c < HH; ++c) a = fmaf(hid[g * HH + c], w2[c * GOUT + u], a);
            ob[i] = a;
        }
    }
}

extern "C" void kernel_launch(void* const* d_in, const int* in_sizes, int n_in,
                              void* d_out, int out_size, void* d_ws, size_t ws_size,
                              hipStream_t stream)
{
    const float* x     = (const float*)d_in[0];
    const int*   ei    = (const int*)d_in[1];
    const float* ea    = (const float*)d_in[2];
    const int*   batch = (const int*)d_in[3];
    const float* w_emb = (const float*)d_in[4];
    const float* b_emb = (const float*)d_in[5];
    const float* gamma = (const float*)d_in[6];
    const float* beta  = (const float*)d_in[7];
    const float* cw1   = (const float*)d_in[8];
    const float* cb1   = (const float*)d_in[9];
    const float* cw2   = (const float*)d_in[10];
    const float* cb2   = (const float*)d_in[11];
    const float* croot = (const float*)d_in[12];
    const float* cbias = (const float*)d_in[13];
    float* out = (float*)d_out;

    float* ws    = (float*)d_ws;
    float* h0    = ws;
    float* h1    = h0 + (size_t)NN * HH;
    float* agg   = h1 + (size_t)NN * HH;
    float* deg   = agg + (size_t)NN * HH;
    float* stats = deg + NN;            // 64
    float* pool  = stats + 64;          // NGR*HH
    float* cnt   = pool + NGR * HH;     // NGR
    float* bnp   = cnt + NGR;           // 64

    // zero all accumulators (deg, stats, pool, cnt are contiguous)
    hipMemsetAsync(deg, 0, (size_t)(NN + 64 + NGR * HH + NGR) * sizeof(float), stream);

    embed_kernel<<<(NN + 255) / 256, 256, 0, stream>>>(x, w_emb, b_emb, h0, stats);
    deg_kernel<<<(NE + 255) / 256, 256, 0, stream>>>(ei, deg);
    bn_finalize<<<1, 32, 0, stream>>>(stats, gamma, beta, bnp);
    bn_apply<<<(NN * HH / 4 + 255) / 256, 256, 0, stream>>>(h0, bnp);

    float* hc = h0;
    float* hn = h1;
    for (int l = 0; l < NL; ++l) {
        hipMemsetAsync(agg, 0, (size_t)NN * HH * sizeof(float), stream);
        edge_kernel<<<(NE + 255) / 256, 256, 0, stream>>>(
            hc, ei, ea, cw1 + l * 4 * 64, cb1 + l * 64,
            cw2 + l * 64 * HH * HH, cb2 + l * HH * HH, agg);
        node_kernel<<<(NN + 255) / 256, 256, 0, stream>>>(
            hc, agg, deg, croot + l * HH * HH, cbias + l * HH, hn);
        float* t = hc; hc = hn; hn = t;
    }

    pool_kernel<<<(NN + 255) / 256, 256, 0, stream>>>(hc, batch, pool, cnt);
    heads_kernel<<<3, 256, 0, stream>>>(pool, cnt,
        (const float*)d_in[14], (const float*)d_in[15], (const float*)d_in[16], (const float*)d_in[17],
        (const float*)d_in[18], (const float*)d_in[19], (const float*)d_in[20], (const float*)d_in[21],
        (const float*)d_in[22], (const float*)d_in[23], (const float*)d_in[24], (const float*)d_in[25],
        out);
}

// Round 2
// 778.841 us; speedup vs baseline: 3.6109x; 3.6109x over previous
//
#include <hip/hip_runtime.h>

#define NN 100000
#define NE 200000
#define HH 32
#define NL 4
#define NGR 50
#define GOUT 100
#define NODE_IN 6
#define NEB 782  // ceil(NE/256)

typedef __attribute__((ext_vector_type(8))) short bf16x8;
typedef __attribute__((ext_vector_type(4))) float f32x4;

__device__ __forceinline__ unsigned short bf16_rne(float x) {
    unsigned int b = __float_as_uint(x);
    b += 0x7FFFu + ((b >> 16) & 1u);
    return (unsigned short)(b >> 16);
}
__device__ __forceinline__ float bf16_f(unsigned short h) {
    return __uint_as_float(((unsigned int)h) << 16);
}

// ---------------- w2 -> transposed bf16 hi/lo split: w2t[l][n][k] ----------------
__global__ __launch_bounds__(256) void split_w2(const float* __restrict__ w2,
                                                unsigned short* __restrict__ w2h,
                                                unsigned short* __restrict__ w2l)
{
    int id = blockIdx.x * 256 + threadIdx.x;
    if (id >= NL * 64 * 1024) return;
    int l = id >> 16, rem = id & 65535;
    int k = rem >> 10, n = rem & 1023;
    float v = w2[id];
    unsigned short hi = bf16_rne(v);
    float lov = v - bf16_f(hi);
    unsigned short lo = bf16_rne(lov);
    int out = l * 65536 + n * 64 + k;
    w2h[out] = hi;
    w2l[out] = lo;
}

// ---------------- embed: h0 = relu(x @ w_emb + b_emb), partial BN stats ----------------
__global__ __launch_bounds__(256) void embed_kernel(
    const float* __restrict__ x, const float* __restrict__ w,
    const float* __restrict__ b, float* __restrict__ h0,
    float* __restrict__ stats)
{
    __shared__ float ls[64];
    int tid = threadIdx.x;
    if (tid < 64) ls[tid] = 0.f;
    __syncthreads();
    int nid = blockIdx.x * 256 + tid;
    if (nid < NN) {
        float xv[NODE_IN];
        #pragma unroll
        for (int d = 0; d < NODE_IN; ++d) xv[d] = x[nid * NODE_IN + d];
        #pragma unroll
        for (int j = 0; j < HH; ++j) {
            float a = b[j];
            #pragma unroll
            for (int d = 0; d < NODE_IN; ++d) a = fmaf(xv[d], w[d * HH + j], a);
            a = fmaxf(a, 0.f);
            h0[nid * HH + j] = a;
            atomicAdd(&ls[j], a);
            atomicAdd(&ls[32 + j], a * a);
        }
    }
    __syncthreads();
    if (tid < 64) unsafeAtomicAdd(&stats[tid], ls[tid]);
}

__global__ __launch_bounds__(256) void deg_kernel(const int* __restrict__ ei,
                                                  float* __restrict__ deg)
{
    int e = blockIdx.x * 256 + threadIdx.x;
    if (e >= NE) return;
    unsafeAtomicAdd(&deg[ei[NE + e]], 1.0f);
}

__global__ void bn_finalize(const float* __restrict__ stats,
                            const float* __restrict__ gamma,
                            const float* __restrict__ beta,
                            float* __restrict__ bnp)
{
    int j = threadIdx.x;
    if (j >= HH) return;
    const float invn = 1.0f / (float)NN;
    float mu  = stats[j] * invn;
    float var = stats[32 + j] * invn - mu * mu;
    float rs  = 1.0f / sqrtf(var + 1e-5f);
    float sc  = rs * gamma[j];
    bnp[j]      = sc;
    bnp[32 + j] = beta[j] - mu * sc;
}

__global__ __launch_bounds__(256) void bn_apply(float* __restrict__ h,
                                                const float* __restrict__ bnp)
{
    int idx = blockIdx.x * 256 + threadIdx.x;
    if (idx >= NN * HH / 4) return;
    float4 v = ((float4*)h)[idx];
    int j = (idx * 4) & 31;
    v.x = fmaf(v.x, bnp[j + 0], bnp[32 + j + 0]);
    v.y = fmaf(v.y, bnp[j + 1], bnp[32 + j + 1]);
    v.z = fmaf(v.z, bnp[j + 2], bnp[32 + j + 2]);
    v.w = fmaf(v.w, bnp[j + 3], bnp[32 + j + 3]);
    ((float4*)h)[idx] = v;
}

// ---------------- NNConv edge kernel via MFMA (split-bf16 T @ w2, fused fold) ---------
// G[e, n] = sum_k T[e,k] * w2[k, n]   (n = i*32+o, split-bf16, 3 MFMA terms)
// msg[e,o] = sum_i h[e,i] * (G[e, i*32+o] + b2[i*32+o])  (fp32 VALU fold, fixed i/ntile)
__global__ __launch_bounds__(256) void edge_mfma(
    const float* __restrict__ h, const int* __restrict__ ei,
    const float* __restrict__ ea,
    const float* __restrict__ w1, const float* __restrict__ b1,
    const unsigned short* __restrict__ w2h, const unsigned short* __restrict__ w2l,
    const float* __restrict__ b2, float* __restrict__ agg)
{
    __shared__ float hT[32 * 256];          // [i][e_local] f32, 32 KB
    __shared__ float b2l[1024];             // 4 KB
    __shared__ int   dstl[256];             // 1 KB
    __shared__ unsigned short Bh[8192];     // 16 KB: 128 rows(n) x 64 k bf16, XOR-swizzled
    __shared__ unsigned short Bl[8192];     // 16 KB

    const int tid  = threadIdx.x;
    const int w    = tid >> 6;
    const int lane = tid & 63;
    const int l15  = lane & 15;
    const int lg   = lane >> 4;            // 0..3
    const int eb   = blockIdx.x * 256;

    // ---- stage per-block edge data ----
    {
        int e = eb + tid;
        int s = 0, d = 0;
        if (e < NE) { s = ei[e]; d = ei[NE + e]; }
        dstl[tid] = d;
        const float4* hp = (const float4*)(h + (size_t)s * HH);
        #pragma unroll
        for (int q = 0; q < 8; ++q) {
            float4 v = hp[q];
            hT[(q * 4 + 0) * 256 + tid] = v.x;
            hT[(q * 4 + 1) * 256 + tid] = v.y;
            hT[(q * 4 + 2) * 256 + tid] = v.z;
            hT[(q * 4 + 3) * 256 + tid] = v.w;
        }
        ((float4*)b2l)[tid] = ((const float4*)b2)[tid];   // 256*4 = 1024
    }

    // ---- compute A-operand fragments: T = relu(ea@w1+b1), split hi/lo bf16 ----
    // A layout (16x16x32): lane holds T[e = l15][k = ks*32 + lg*8 + j]
    bf16x8 thi[4][2], tlo[4][2];
    #pragma unroll
    for (int et = 0; et < 4; ++et) {
        int e = eb + w * 64 + et * 16 + l15;
        bool ev = (e < NE);
        float4 eav = make_float4(0.f, 0.f, 0.f, 0.f);
        if (ev) eav = *(const float4*)(ea + (size_t)e * 4);
        #pragma unroll
        for (int ks = 0; ks < 2; ++ks) {
            int k0 = ks * 32 + lg * 8;
            #pragma unroll
            for (int j = 0; j < 8; ++j) {
                float t = b1[k0 + j];
                t = fmaf(eav.x, w1[0 * 64 + k0 + j], t);
                t = fmaf(eav.y, w1[1 * 64 + k0 + j], t);
                t = fmaf(eav.z, w1[2 * 64 + k0 + j], t);
                t = fmaf(eav.w, w1[3 * 64 + k0 + j], t);
                t = ev ? fmaxf(t, 0.f) : 0.f;
                unsigned short hi = bf16_rne(t);
                float lov = t - bf16_f(hi);
                unsigned short lo = bf16_rne(lov);
                thi[et][ks][j] = (short)hi;
                tlo[et][ks][j] = (short)lo;
            }
        }
    }

    float acc0[4][4], acc1[4][4];
    #pragma unroll
    for (int et = 0; et < 4; ++et)
        #pragma unroll
        for (int r = 0; r < 4; ++r) { acc0[et][r] = 0.f; acc1[et][r] = 0.f; }

    // ---- main loop: 8 n-chunks of 128 columns ----
    for (int c = 0; c < 8; ++c) {
        __syncthreads();   // prior chunk consumed (and hT staging complete at c==0)
        {   // stage B chunk (XOR-swizzled granules so frag reads are conflict-free)
            const uint4* gh = (const uint4*)w2h;
            const uint4* gl = (const uint4*)w2l;
            #pragma unroll
            for (int q = 0; q < 4; ++q) {
                int g = q * 256 + tid;          // 16B granule id, 1024 total
                int n = g >> 3, j = g & 7;
                int gi = (c * 128 + n) * 8 + (j ^ (n & 7));
                ((uint4*)Bh)[g] = gh[gi];
                ((uint4*)Bl)[g] = gl[gi];
            }
        }
        __syncthreads();

        for (int ntp = 0; ntp < 4; ++ntp) {
            int i = c * 4 + ntp;               // h row for this ntile pair
            #pragma unroll
            for (int half = 0; half < 2; ++half) {
                int nt = ntp * 2 + half;
                int nl = nt * 16 + l15;        // B row (chunk-local n)
                int swz = (nl & 7) << 4;
                const char* bhrow = (const char*)Bh + nl * 128;
                const char* blrow = (const char*)Bl + nl * 128;
                bf16x8 Bh0 = *(const bf16x8*)(bhrow + (( 0 + lg * 16) ^ swz));
                bf16x8 Bl0 = *(const bf16x8*)(blrow + (( 0 + lg * 16) ^ swz));
                bf16x8 Bh1 = *(const bf16x8*)(bhrow + ((64 + lg * 16) ^ swz));
                bf16x8 Bl1 = *(const bf16x8*)(blrow + ((64 + lg * 16) ^ swz));
                float b2v = b2l[c * 128 + nt * 16 + l15];
                #pragma unroll
                for (int et = 0; et < 4; ++et) {
                    f32x4 G = {0.f, 0.f, 0.f, 0.f};
                    G = __builtin_amdgcn_mfma_f32_16x16x32_bf16(thi[et][0], Bh0, G, 0, 0, 0);
                    G = __builtin_amdgcn_mfma_f32_16x16x32_bf16(tlo[et][0], Bh0, G, 0, 0, 0);
                    G = __builtin_amdgcn_mfma_f32_16x16x32_bf16(thi[et][0], Bl0, G, 0, 0, 0);
                    G = __builtin_amdgcn_mfma_f32_16x16x32_bf16(thi[et][1], Bh1, G, 0, 0, 0);
                    G = __builtin_amdgcn_mfma_f32_16x16x32_bf16(tlo[et][1], Bh1, G, 0, 0, 0);
                    G = __builtin_amdgcn_mfma_f32_16x16x32_bf16(thi[et][1], Bl1, G, 0, 0, 0);
                    const float4 h4 = *(const float4*)&hT[i * 256 + w * 64 + et * 16 + lg * 4];
                    if (half == 0) {
                        acc0[et][0] = fmaf(h4.x, G[0] + b2v, acc0[et][0]);
                        acc0[et][1] = fmaf(h4.y, G[1] + b2v, acc0[et][1]);
                        acc0[et][2] = fmaf(h4.z, G[2] + b2v, acc0[et][2]);
                        acc0[et][3] = fmaf(h4.w, G[3] + b2v, acc0[et][3]);
                    } else {
                        acc1[et][0] = fmaf(h4.x, G[0] + b2v, acc1[et][0]);
                        acc1[et][1] = fmaf(h4.y, G[1] + b2v, acc1[et][1]);
                        acc1[et][2] = fmaf(h4.z, G[2] + b2v, acc1[et][2]);
                        acc1[et][3] = fmaf(h4.w, G[3] + b2v, acc1[et][3]);
                    }
                }
            }
        }
    }

    // ---- scatter (atomic mean numerator) ----
    #pragma unroll
    for (int et = 0; et < 4; ++et) {
        int eloc = w * 64 + et * 16 + lg * 4;
        int4 d4 = *(const int4*)&dstl[eloc];
        #pragma unroll
        for (int r = 0; r < 4; ++r) {
            int eg = eb + eloc + r;
            if (eg < NE) {
                int dd = (r == 0) ? d4.x : (r == 1) ? d4.y : (r == 2) ? d4.z : d4.w;
                unsafeAtomicAdd(agg + (size_t)dd * HH + l15,      acc0[et][r]);
                unsafeAtomicAdd(agg + (size_t)dd * HH + 16 + l15, acc1[et][r]);
            }
        }
    }
}

// ---------------- node update: h' = relu(agg*inv_deg + h@root + bias) ----------------
__global__ __launch_bounds__(256) void node_kernel(
    const float* __restrict__ h, const float* __restrict__ agg,
    const float* __restrict__ deg, const float* __restrict__ root,
    const float* __restrict__ bias, float* __restrict__ hout)
{
    int nid = blockIdx.x * 256 + threadIdx.x;
    if (nid >= NN) return;
    float hv[HH];
    {
        const float4* hp = (const float4*)(h + nid * HH);
        #pragma unroll
        for (int q = 0; q < 8; ++q) {
            float4 v = hp[q];
            hv[4*q+0] = v.x; hv[4*q+1] = v.y; hv[4*q+2] = v.z; hv[4*q+3] = v.w;
        }
    }
    float inv = 1.0f / fmaxf(deg[nid], 1.0f);
    float acc[HH];
    #pragma unroll
    for (int o = 0; o < HH; ++o) acc[o] = bias[o];
    #pragma unroll
    for (int i = 0; i < HH; ++i) {
        float hi = hv[i];
        #pragma unroll
        for (int o = 0; o < HH; ++o) acc[o] = fmaf(hi, root[i * HH + o], acc[o]);
    }
    const float4* av = (const float4*)(agg + nid * HH);
    #pragma unroll
    for (int q = 0; q < 8; ++q) {
        float4 a = av[q];
        float4 r;
        r.x = fmaxf(fmaf(a.x, inv, acc[4*q+0]), 0.f);
        r.y = fmaxf(fmaf(a.y, inv, acc[4*q+1]), 0.f);
        r.z = fmaxf(fmaf(a.z, inv, acc[4*q+2]), 0.f);
        r.w = fmaxf(fmaf(a.w, inv, acc[4*q+3]), 0.f);
        ((float4*)(hout + nid * HH))[q] = r;
    }
}

// ---------------- global mean pool ----------------
__global__ __launch_bounds__(256) void pool_kernel(
    const float* __restrict__ h, const int* __restrict__ batch,
    float* __restrict__ pool, float* __restrict__ cnt)
{
    __shared__ float lp[NGR * HH];
    __shared__ float lc[NGR];
    int tid = threadIdx.x;
    for (int i = tid; i < NGR * HH; i += 256) lp[i] = 0.f;
    for (int i = tid; i < NGR; i += 256) lc[i] = 0.f;
    __syncthreads();
    int nid = blockIdx.x * 256 + tid;
    if (nid < NN) {
        int g = batch[nid];
        atomicAdd(&lc[g], 1.0f);
        #pragma unroll
        for (int j = 0; j < HH; ++j) atomicAdd(&lp[g * HH + j], h[nid * HH + j]);
    }
    __syncthreads();
    for (int i = tid; i < NGR * HH; i += 256)
        if (lp[i] != 0.f) unsafeAtomicAdd(&pool[i], lp[i]);
    for (int i = tid; i < NGR; i += 256)
        if (lc[i] != 0.f) unsafeAtomicAdd(&cnt[i], lc[i]);
}

// ---------------- heads ----------------
__global__ __launch_bounds__(256) void heads_kernel(
    const float* __restrict__ pool, const float* __restrict__ cnt,
    const float* __restrict__ wkw1, const float* __restrict__ wkb1,
    const float* __restrict__ wkw2, const float* __restrict__ wkb2,
    const float* __restrict__ ujw1, const float* __restrict__ ujb1,
    const float* __restrict__ ujw2, const float* __restrict__ ujb2,
    const float* __restrict__ zkw1, const float* __restrict__ zkb1,
    const float* __restrict__ zkw2, const float* __restrict__ zkb2,
    float* __restrict__ out)
{
    __shared__ float hg[NGR * HH];
    __shared__ float hid[NGR * HH];
    int tid = threadIdx.x;
    int head = blockIdx.x;
    const float *w1, *b1, *w2, *b2;
    if (head == 0)      { w1 = wkw1; b1 = wkb1; w2 = wkw2; b2 = wkb2; }
    else if (head == 1) { w1 = ujw1; b1 = ujb1; w2 = ujw2; b2 = ujb2; }
    else                { w1 = zkw1; b1 = zkb1; w2 = zkw2; b2 = zkb2; }
    for (int i = tid; i < NGR * HH; i += 256) {
        int g = i >> 5;
        hg[i] = pool[i] / fmaxf(cnt[g], 1.0f);
    }
    __syncthreads();
    for (int i = tid; i < NGR * HH; i += 256) {
        int g = i >> 5, c = i & 31;
        float a = b1[c];
        for (int j = 0; j < HH; ++j) a = fmaf(hg[g * HH + j], w1[j * HH + c], a);
        hid[i] = fmaxf(a, 0.f);
    }
    __syncthreads();
    if (head == 0) {
        if (tid < NGR) {
            float a = b2[0];
            for (int c = 0; c < HH; ++c) a = fmaf(hid[tid * HH + c], w2[c], a);
            out[tid] = a;
        }
    } else {
        float* ob = out + NGR + (head - 1) * NGR * GOUT;
        for (int i = tid; i < NGR * GOUT; i += 256) {
            int g = i / GOUT, u = i % GOUT;
            float a = b2[u];
            for (int c = 0; c < HH; ++c) a = fmaf(hid[g * HH + c], w2[c * GOUT + u], a);
            ob[i] = a;
        }
    }
}

extern "C" void kernel_launch(void* const* d_in, const int* in_sizes, int n_in,
                              void* d_out, int out_size, void* d_ws, size_t ws_size,
                              hipStream_t stream)
{
    const float* x     = (const float*)d_in[0];
    const int*   ei    = (const int*)d_in[1];
    const float* ea    = (const float*)d_in[2];
    const int*   batch = (const int*)d_in[3];
    const float* w_emb = (const float*)d_in[4];
    const float* b_emb = (const float*)d_in[5];
    const float* gamma = (const float*)d_in[6];
    const float* beta  = (const float*)d_in[7];
    const float* cw1   = (const float*)d_in[8];
    const float* cb1   = (const float*)d_in[9];
    const float* cw2   = (const float*)d_in[10];
    const float* cb2   = (const float*)d_in[11];
    const float* croot = (const float*)d_in[12];
    const float* cbias = (const float*)d_in[13];
    float* out = (float*)d_out;

    // ws layout: bf16 split tables first (16B aligned), then fp32 scratch
    unsigned short* w2h = (unsigned short*)d_ws;          // NL*65536
    unsigned short* w2l = w2h + (size_t)NL * 65536;       // NL*65536
    float* h0    = (float*)(w2l + (size_t)NL * 65536);
    float* h1    = h0 + (size_t)NN * HH;
    float* agg   = h1 + (size_t)NN * HH;
    float* deg   = agg + (size_t)NN * HH;
    float* stats = deg + NN;            // 64
    float* pool  = stats + 64;          // NGR*HH
    float* cnt   = pool + NGR * HH;     // NGR
    float* bnp   = cnt + NGR;           // 64

    hipMemsetAsync(deg, 0, (size_t)(NN + 64 + NGR * HH + NGR) * sizeof(float), stream);

    split_w2<<<(NL * 65536) / 256, 256, 0, stream>>>(cw2, w2h, w2l);
    embed_kernel<<<(NN + 255) / 256, 256, 0, stream>>>(x, w_emb, b_emb, h0, stats);
    deg_kernel<<<(NE + 255) / 256, 256, 0, stream>>>(ei, deg);
    bn_finalize<<<1, 32, 0, stream>>>(stats, gamma, beta, bnp);
    bn_apply<<<(NN * HH / 4 + 255) / 256, 256, 0, stream>>>(h0, bnp);

    float* hc = h0;
    float* hn = h1;
    for (int l = 0; l < NL; ++l) {
        hipMemsetAsync(agg, 0, (size_t)NN * HH * sizeof(float), stream);
        edge_mfma<<<NEB, 256, 0, stream>>>(
            hc, ei, ea,
            cw1 + (size_t)l * 4 * 64, cb1 + (size_t)l * 64,
            w2h + (size_t)l * 65536, w2l + (size_t)l * 65536,
            cb2 + (size_t)l * 1024, agg);
        node_kernel<<<(NN + 255) / 256, 256, 0, stream>>>(
            hc, agg, deg, croot + (size_t)l * HH * HH, cbias + (size_t)l * HH, hn);
        float* t = hc; hc = hn; hn = t;
    }

    pool_kernel<<<(NN + 255) / 256, 256, 0, stream>>>(hc, batch, pool, cnt);
    heads_kernel<<<3, 256, 0, stream>>>(pool, cnt,
        (const float*)d_in[14], (const float*)d_in[15], (const float*)d_in[16], (const float*)d_in[17],
        (const float*)d_in[18], (const float*)d_in[19], (const float*)d_in[20], (const float*)d_in[21],
        (const float*)d_in[22], (const float*)d_in[23], (const float*)d_in[24], (const float*)d_in[25],
        out);
}

// Round 3
// 701.435 us; speedup vs baseline: 4.0094x; 1.1104x over previous
//
#include <hip/hip_runtime.h>

#define NN 100000
#define NE 200000
#define HH 32
#define NL 4
#define NGR 50
#define GOUT 100
#define NODE_IN 6
#define NEB 782  // ceil(NE/256)

typedef __attribute__((ext_vector_type(8))) short bf16x8;
typedef __attribute__((ext_vector_type(4))) float f32x4;

__device__ __forceinline__ unsigned short bf16_rne(float x) {
    unsigned int b = __float_as_uint(x);
    b += 0x7FFFu + ((b >> 16) & 1u);
    return (unsigned short)(b >> 16);
}
__device__ __forceinline__ float bf16_f(unsigned short h) {
    return __uint_as_float(((unsigned int)h) << 16);
}

// ---------------- w2 -> transposed bf16 hi/lo split: w2t[l][n][k] ----------------
__global__ __launch_bounds__(256) void split_w2(const float* __restrict__ w2,
                                                unsigned short* __restrict__ w2h,
                                                unsigned short* __restrict__ w2l)
{
    int id = blockIdx.x * 256 + threadIdx.x;
    if (id >= NL * 64 * 1024) return;
    int l = id >> 16, rem = id & 65535;
    int k = rem >> 10, n = rem & 1023;
    float v = w2[id];
    unsigned short hi = bf16_rne(v);
    float lov = v - bf16_f(hi);
    unsigned short lo = bf16_rne(lov);
    int out = l * 65536 + n * 64 + k;
    w2h[out] = hi;
    w2l[out] = lo;
}

// ---------------- embed: h0 = relu(x @ w_emb + b_emb) (no stats) ----------------
__global__ __launch_bounds__(256) void embed_kernel(
    const float* __restrict__ x, const float* __restrict__ w,
    const float* __restrict__ b, float* __restrict__ h0)
{
    int nid = blockIdx.x * 256 + threadIdx.x;
    if (nid >= NN) return;
    float xv[NODE_IN];
    #pragma unroll
    for (int d = 0; d < NODE_IN; ++d) xv[d] = x[nid * NODE_IN + d];
    float4* op = (float4*)(h0 + (size_t)nid * HH);
    #pragma unroll
    for (int q = 0; q < 8; ++q) {
        float4 r;
        float* rp = (float*)&r;
        #pragma unroll
        for (int u = 0; u < 4; ++u) {
            int j = q * 4 + u;
            float a = b[j];
            #pragma unroll
            for (int d = 0; d < NODE_IN; ++d) a = fmaf(xv[d], w[d * HH + j], a);
            rp[u] = fmaxf(a, 0.f);
        }
        op[q] = r;
    }
}

// ---------------- BN stats: per-column sum & sumsq via register partials ----------------
__global__ __launch_bounds__(256) void stats_kernel(const float* __restrict__ h0,
                                                    float* __restrict__ stats)
{
    __shared__ float ls[64];
    int tid = threadIdx.x;
    if (tid < 64) ls[tid] = 0.f;
    __syncthreads();
    float s[4] = {0.f, 0.f, 0.f, 0.f};
    float q[4] = {0.f, 0.f, 0.f, 0.f};
    const float4* h4 = (const float4*)h0;
    const int total = NN * HH / 4;           // 800000
    for (int idx = blockIdx.x * 256 + tid; idx < total; idx += 128 * 256) {
        float4 v = h4[idx];
        s[0] += v.x; q[0] += v.x * v.x;
        s[1] += v.y; q[1] += v.y * v.y;
        s[2] += v.z; q[2] += v.z * v.z;
        s[3] += v.w; q[3] += v.w * v.w;
    }
    int c0 = (tid * 4) & 31;                 // fixed: stride 32768*4 floats ≡ 0 mod 32
    #pragma unroll
    for (int u = 0; u < 4; ++u) {
        atomicAdd(&ls[c0 + u], s[u]);
        atomicAdd(&ls[32 + c0 + u], q[u]);
    }
    __syncthreads();
    if (tid < 64) unsafeAtomicAdd(&stats[tid], ls[tid]);
}

__global__ __launch_bounds__(256) void deg_kernel(const int* __restrict__ ei,
                                                  float* __restrict__ deg)
{
    int e = blockIdx.x * 256 + threadIdx.x;
    if (e >= NE) return;
    unsafeAtomicAdd(&deg[ei[NE + e]], 1.0f);
}

__global__ void bn_finalize(const float* __restrict__ stats,
                            const float* __restrict__ gamma,
                            const float* __restrict__ beta,
                            float* __restrict__ bnp)
{
    int j = threadIdx.x;
    if (j >= HH) return;
    const float invn = 1.0f / (float)NN;
    float mu  = stats[j] * invn;
    float var = stats[32 + j] * invn - mu * mu;
    float rs  = 1.0f / sqrtf(var + 1e-5f);
    float sc  = rs * gamma[j];
    bnp[j]      = sc;
    bnp[32 + j] = beta[j] - mu * sc;
}

__global__ __launch_bounds__(256) void bn_apply(float* __restrict__ h,
                                                const float* __restrict__ bnp)
{
    int idx = blockIdx.x * 256 + threadIdx.x;
    if (idx >= NN * HH / 4) return;
    float4 v = ((float4*)h)[idx];
    int j = (idx * 4) & 31;
    v.x = fmaf(v.x, bnp[j + 0], bnp[32 + j + 0]);
    v.y = fmaf(v.y, bnp[j + 1], bnp[32 + j + 1]);
    v.z = fmaf(v.z, bnp[j + 2], bnp[32 + j + 2]);
    v.w = fmaf(v.w, bnp[j + 3], bnp[32 + j + 3]);
    ((float4*)h)[idx] = v;
}

// ---------------- NNConv edge kernel via MFMA, async double-buffered B staging -------
// G[e, n] = sum_k T[e,k] * w2[k, n]   (n = i*32+o, split-bf16, 3 MFMA terms)
// msg[e,o] = sum_i h[e,i] * (G[e, i*32+o] + b2[i*32+o])  (fp32 VALU fold)
__global__ __launch_bounds__(256) void edge_mfma(
    const float* __restrict__ h, const int* __restrict__ ei,
    const float* __restrict__ ea,
    const float* __restrict__ w1, const float* __restrict__ b1,
    const unsigned short* __restrict__ w2h, const unsigned short* __restrict__ w2l,
    const float* __restrict__ b2, float* __restrict__ agg)
{
    __shared__ float hT[32 * 256];              // 32 KB
    __shared__ float b2l[1024];                 // 4 KB
    __shared__ int   dstl[256];                 // 1 KB
    __shared__ unsigned short Bh[2][4096];      // 2 x 8 KB: 64 n-rows x 64 k, swizzled
    __shared__ unsigned short Bl[2][4096];      // 2 x 8 KB

    const int tid  = threadIdx.x;
    const int w    = tid >> 6;
    const int lane = tid & 63;
    const int l15  = lane & 15;
    const int lg   = lane >> 4;                 // 0..3
    const int eb   = blockIdx.x * 256;

    const unsigned int* gh = (const unsigned int*)w2h;   // granule = 16 B = 4 uints
    const unsigned int* gl = (const unsigned int*)w2l;
    const int wavebase = tid & ~63;             // w*64

    // ---- async stage: chunk c2 (64 n-cols) into buffer buf ----
    auto stage = [&](int c2, int buf) {
        #pragma unroll
        for (int q = 0; q < 2; ++q) {
            int g = q * 256 + tid;               // granule id 0..511
            int n = g >> 3, j = g & 7;
            int gi = ((c2 * 64 + n) << 3) + (j ^ (n & 7));
            int lb = (q * 256 + wavebase) * 8;   // shorts; wave-uniform
            __builtin_amdgcn_global_load_lds(
                (const __attribute__((address_space(1))) unsigned int*)(gh + (size_t)gi * 4),
                (__attribute__((address_space(3))) unsigned int*)(&Bh[buf][0] + lb), 16, 0, 0);
            __builtin_amdgcn_global_load_lds(
                (const __attribute__((address_space(1))) unsigned int*)(gl + (size_t)gi * 4),
                (__attribute__((address_space(3))) unsigned int*)(&Bl[buf][0] + lb), 16, 0, 0);
        }
    };

    stage(0, 0);   // prefetch first chunk while we do all the setup below

    // ---- stage per-block edge data ----
    {
        int e = eb + tid;
        int s = 0, d = 0;
        if (e < NE) { s = ei[e]; d = ei[NE + e]; }
        dstl[tid] = d;
        const float4* hp = (const float4*)(h + (size_t)s * HH);
        #pragma unroll
        for (int q = 0; q < 8; ++q) {
            float4 v = hp[q];
            hT[(q * 4 + 0) * 256 + tid] = v.x;
            hT[(q * 4 + 1) * 256 + tid] = v.y;
            hT[(q * 4 + 2) * 256 + tid] = v.z;
            hT[(q * 4 + 3) * 256 + tid] = v.w;
        }
        ((float4*)b2l)[tid] = ((const float4*)b2)[tid];
    }

    // ---- A-operand fragments: T = relu(ea@w1+b1), split hi/lo bf16 ----
    bf16x8 thi[4][2], tlo[4][2];
    #pragma unroll
    for (int et = 0; et < 4; ++et) {
        int e = eb + w * 64 + et * 16 + l15;
        bool ev = (e < NE);
        float4 eav = make_float4(0.f, 0.f, 0.f, 0.f);
        if (ev) eav = *(const float4*)(ea + (size_t)e * 4);
        #pragma unroll
        for (int ks = 0; ks < 2; ++ks) {
            int k0 = ks * 32 + lg * 8;
            #pragma unroll
            for (int j = 0; j < 8; ++j) {
                float t = b1[k0 + j];
                t = fmaf(eav.x, w1[0 * 64 + k0 + j], t);
                t = fmaf(eav.y, w1[1 * 64 + k0 + j], t);
                t = fmaf(eav.z, w1[2 * 64 + k0 + j], t);
                t = fmaf(eav.w, w1[3 * 64 + k0 + j], t);
                t = ev ? fmaxf(t, 0.f) : 0.f;
                unsigned short hi = bf16_rne(t);
                float lov = t - bf16_f(hi);
                unsigned short lo = bf16_rne(lov);
                thi[et][ks][j] = (short)hi;
                tlo[et][ks][j] = (short)lo;
            }
        }
    }

    float acc0[4][4], acc1[4][4];
    #pragma unroll
    for (int et = 0; et < 4; ++et)
        #pragma unroll
        for (int r = 0; r < 4; ++r) { acc0[et][r] = 0.f; acc1[et][r] = 0.f; }

    // ---- main loop: 16 chunks of 64 n-cols, double-buffered ----
    for (int c2 = 0; c2 < 16; ++c2) {
        const int buf = c2 & 1;
        __syncthreads();                 // chunk c2 staged (vmcnt drained), prev compute done
        if (c2 < 15) stage(c2 + 1, buf ^ 1);

        #pragma unroll
        for (int ntp = 0; ntp < 2; ++ntp) {
            const int i = c2 * 2 + ntp;  // h row for this 32-col pair
            float4 h4[4];
            #pragma unroll
            for (int et = 0; et < 4; ++et)
                h4[et] = *(const float4*)&hT[i * 256 + wavebase + et * 16 + lg * 4];
            #pragma unroll
            for (int half = 0; half < 2; ++half) {
                int nt = ntp * 2 + half;           // 0..3 within chunk
                int nl = nt * 16 + l15;            // chunk-local n row
                int swz = (nl & 7) << 4;
                const char* bhrow = (const char*)&Bh[buf][0] + nl * 128;
                const char* blrow = (const char*)&Bl[buf][0] + nl * 128;
                bf16x8 Bh0 = *(const bf16x8*)(bhrow + (( 0 + lg * 16) ^ swz));
                bf16x8 Bl0 = *(const bf16x8*)(blrow + (( 0 + lg * 16) ^ swz));
                bf16x8 Bh1 = *(const bf16x8*)(bhrow + ((64 + lg * 16) ^ swz));
                bf16x8 Bl1 = *(const bf16x8*)(blrow + ((64 + lg * 16) ^ swz));
                float b2v = b2l[c2 * 64 + nt * 16 + l15];
                #pragma unroll
                for (int et = 0; et < 4; ++et) {
                    f32x4 G = {0.f, 0.f, 0.f, 0.f};
                    G = __builtin_amdgcn_mfma_f32_16x16x32_bf16(thi[et][0], Bh0, G, 0, 0, 0);
                    G = __builtin_amdgcn_mfma_f32_16x16x32_bf16(tlo[et][0], Bh0, G, 0, 0, 0);
                    G = __builtin_amdgcn_mfma_f32_16x16x32_bf16(thi[et][0], Bl0, G, 0, 0, 0);
                    G = __builtin_amdgcn_mfma_f32_16x16x32_bf16(thi[et][1], Bh1, G, 0, 0, 0);
                    G = __builtin_amdgcn_mfma_f32_16x16x32_bf16(tlo[et][1], Bh1, G, 0, 0, 0);
                    G = __builtin_amdgcn_mfma_f32_16x16x32_bf16(thi[et][1], Bl1, G, 0, 0, 0);
                    if (half == 0) {
                        acc0[et][0] = fmaf(h4[et].x, G[0] + b2v, acc0[et][0]);
                        acc0[et][1] = fmaf(h4[et].y, G[1] + b2v, acc0[et][1]);
                        acc0[et][2] = fmaf(h4[et].z, G[2] + b2v, acc0[et][2]);
                        acc0[et][3] = fmaf(h4[et].w, G[3] + b2v, acc0[et][3]);
                    } else {
                        acc1[et][0] = fmaf(h4[et].x, G[0] + b2v, acc1[et][0]);
                        acc1[et][1] = fmaf(h4[et].y, G[1] + b2v, acc1[et][1]);
                        acc1[et][2] = fmaf(h4[et].z, G[2] + b2v, acc1[et][2]);
                        acc1[et][3] = fmaf(h4[et].w, G[3] + b2v, acc1[et][3]);
                    }
                }
            }
        }
    }

    // ---- scatter ----
    #pragma unroll
    for (int et = 0; et < 4; ++et) {
        int eloc = wavebase + et * 16 + lg * 4;
        int4 d4 = *(const int4*)&dstl[eloc];
        #pragma unroll
        for (int r = 0; r < 4; ++r) {
            int eg = eb + eloc + r;
            if (eg < NE) {
                int dd = (r == 0) ? d4.x : (r == 1) ? d4.y : (r == 2) ? d4.z : d4.w;
                unsafeAtomicAdd(agg + (size_t)dd * HH + l15,      acc0[et][r]);
                unsafeAtomicAdd(agg + (size_t)dd * HH + 16 + l15, acc1[et][r]);
            }
        }
    }
}

// ---------------- node update ----------------
__global__ __launch_bounds__(256) void node_kernel(
    const float* __restrict__ h, const float* __restrict__ agg,
    const float* __restrict__ deg, const float* __restrict__ root,
    const float* __restrict__ bias, float* __restrict__ hout)
{
    int nid = blockIdx.x * 256 + threadIdx.x;
    if (nid >= NN) return;
    float hv[HH];
    {
        const float4* hp = (const float4*)(h + nid * HH);
        #pragma unroll
        for (int q = 0; q < 8; ++q) {
            float4 v = hp[q];
            hv[4*q+0] = v.x; hv[4*q+1] = v.y; hv[4*q+2] = v.z; hv[4*q+3] = v.w;
        }
    }
    float inv = 1.0f / fmaxf(deg[nid], 1.0f);
    float acc[HH];
    #pragma unroll
    for (int o = 0; o < HH; ++o) acc[o] = bias[o];
    #pragma unroll
    for (int i = 0; i < HH; ++i) {
        float hi = hv[i];
        #pragma unroll
        for (int o = 0; o < HH; ++o) acc[o] = fmaf(hi, root[i * HH + o], acc[o]);
    }
    const float4* av = (const float4*)(agg + nid * HH);
    #pragma unroll
    for (int q = 0; q < 8; ++q) {
        float4 a = av[q];
        float4 r;
        r.x = fmaxf(fmaf(a.x, inv, acc[4*q+0]), 0.f);
        r.y = fmaxf(fmaf(a.y, inv, acc[4*q+1]), 0.f);
        r.z = fmaxf(fmaf(a.z, inv, acc[4*q+2]), 0.f);
        r.w = fmaxf(fmaf(a.w, inv, acc[4*q+3]), 0.f);
        ((float4*)(hout + nid * HH))[q] = r;
    }
}

// ---------------- global mean pool ----------------
__global__ __launch_bounds__(256) void pool_kernel(
    const float* __restrict__ h, const int* __restrict__ batch,
    float* __restrict__ pool, float* __restrict__ cnt)
{
    __shared__ float lp[NGR * HH];
    __shared__ float lc[NGR];
    int tid = threadIdx.x;
    for (int i = tid; i < NGR * HH; i += 256) lp[i] = 0.f;
    for (int i = tid; i < NGR; i += 256) lc[i] = 0.f;
    __syncthreads();
    int nid = blockIdx.x * 256 + tid;
    if (nid < NN) {
        int g = batch[nid];
        atomicAdd(&lc[g], 1.0f);
        #pragma unroll
        for (int j = 0; j < HH; ++j) atomicAdd(&lp[g * HH + j], h[nid * HH + j]);
    }
    __syncthreads();
    for (int i = tid; i < NGR * HH; i += 256)
        if (lp[i] != 0.f) unsafeAtomicAdd(&pool[i], lp[i]);
    for (int i = tid; i < NGR; i += 256)
        if (lc[i] != 0.f) unsafeAtomicAdd(&cnt[i], lc[i]);
}

// ---------------- heads ----------------
__global__ __launch_bounds__(256) void heads_kernel(
    const float* __restrict__ pool, const float* __restrict__ cnt,
    const float* __restrict__ wkw1, const float* __restrict__ wkb1,
    const float* __restrict__ wkw2, const float* __restrict__ wkb2,
    const float* __restrict__ ujw1, const float* __restrict__ ujb1,
    const float* __restrict__ ujw2, const float* __restrict__ ujb2,
    const float* __restrict__ zkw1, const float* __restrict__ zkb1,
    const float* __restrict__ zkw2, const float* __restrict__ zkb2,
    float* __restrict__ out)
{
    __shared__ float hg[NGR * HH];
    __shared__ float hid[NGR * HH];
    int tid = threadIdx.x;
    int head = blockIdx.x;
    const float *w1, *b1, *w2, *b2;
    if (head == 0)      { w1 = wkw1; b1 = wkb1; w2 = wkw2; b2 = wkb2; }
    else if (head == 1) { w1 = ujw1; b1 = ujb1; w2 = ujw2; b2 = ujb2; }
    else                { w1 = zkw1; b1 = zkb1; w2 = zkw2; b2 = zkb2; }
    for (int i = tid; i < NGR * HH; i += 256) {
        int g = i >> 5;
        hg[i] = pool[i] / fmaxf(cnt[g], 1.0f);
    }
    __syncthreads();
    for (int i = tid; i < NGR * HH; i += 256) {
        int g = i >> 5, c = i & 31;
        float a = b1[c];
        for (int j = 0; j < HH; ++j) a = fmaf(hg[g * HH + j], w1[j * HH + c], a);
        hid[i] = fmaxf(a, 0.f);
    }
    __syncthreads();
    if (head == 0) {
        if (tid < NGR) {
            float a = b2[0];
            for (int c = 0; c < HH; ++c) a = fmaf(hid[tid * HH + c], w2[c], a);
            out[tid] = a;
        }
    } else {
        float* ob = out + NGR + (head - 1) * NGR * GOUT;
        for (int i = tid; i < NGR * GOUT; i += 256) {
            int g = i / GOUT, u = i % GOUT;
            float a = b2[u];
            for (int c = 0; c < HH; ++c) a = fmaf(hid[g * HH + c], w2[c * GOUT + u], a);
            ob[i] = a;
        }
    }
}

extern "C" void kernel_launch(void* const* d_in, const int* in_sizes, int n_in,
                              void* d_out, int out_size, void* d_ws, size_t ws_size,
                              hipStream_t stream)
{
    const float* x     = (const float*)d_in[0];
    const int*   ei    = (const int*)d_in[1];
    const float* ea    = (const float*)d_in[2];
    const int*   batch = (const int*)d_in[3];
    const float* w_emb = (const float*)d_in[4];
    const float* b_emb = (const float*)d_in[5];
    const float* gamma = (const float*)d_in[6];
    const float* beta  = (const float*)d_in[7];
    const float* cw1   = (const float*)d_in[8];
    const float* cb1   = (const float*)d_in[9];
    const float* cw2   = (const float*)d_in[10];
    const float* cb2   = (const float*)d_in[11];
    const float* croot = (const float*)d_in[12];
    const float* cbias = (const float*)d_in[13];
    float* out = (float*)d_out;

    unsigned short* w2h = (unsigned short*)d_ws;          // NL*65536
    unsigned short* w2l = w2h + (size_t)NL * 65536;       // NL*65536
    float* h0    = (float*)(w2l + (size_t)NL * 65536);
    float* h1    = h0 + (size_t)NN * HH;
    float* agg   = h1 + (size_t)NN * HH;
    float* deg   = agg + (size_t)NN * HH;
    float* stats = deg + NN;            // 64
    float* pool  = stats + 64;          // NGR*HH
    float* cnt   = pool + NGR * HH;     // NGR
    float* bnp   = cnt + NGR;           // 64

    hipMemsetAsync(deg, 0, (size_t)(NN + 64 + NGR * HH + NGR) * sizeof(float), stream);

    split_w2<<<(NL * 65536) / 256, 256, 0, stream>>>(cw2, w2h, w2l);
    embed_kernel<<<(NN + 255) / 256, 256, 0, stream>>>(x, w_emb, b_emb, h0);
    stats_kernel<<<128, 256, 0, stream>>>(h0, stats);
    deg_kernel<<<(NE + 255) / 256, 256, 0, stream>>>(ei, deg);
    bn_finalize<<<1, 32, 0, stream>>>(stats, gamma, beta, bnp);
    bn_apply<<<(NN * HH / 4 + 255) / 256, 256, 0, stream>>>(h0, bnp);

    float* hc = h0;
    float* hn = h1;
    for (int l = 0; l < NL; ++l) {
        hipMemsetAsync(agg, 0, (size_t)NN * HH * sizeof(float), stream);
        edge_mfma<<<NEB, 256, 0, stream>>>(
            hc, ei, ea,
            cw1 + (size_t)l * 4 * 64, cb1 + (size_t)l * 64,
            w2h + (size_t)l * 65536, w2l + (size_t)l * 65536,
            cb2 + (size_t)l * 1024, agg);
        node_kernel<<<(NN + 255) / 256, 256, 0, stream>>>(
            hc, agg, deg, croot + (size_t)l * HH * HH, cbias + (size_t)l * HH, hn);
        float* t = hc; hc = hn; hn = t;
    }

    pool_kernel<<<(NN + 255) / 256, 256, 0, stream>>>(hc, batch, pool, cnt);
    heads_kernel<<<3, 256, 0, stream>>>(pool, cnt,
        (const float*)d_in[14], (const float*)d_in[15], (const float*)d_in[16], (const float*)d_in[17],
        (const float*)d_in[18], (const float*)d_in[19], (const float*)d_in[20], (const float*)d_in[21],
        (const float*)d_in[22], (const float*)d_in[23], (const float*)d_in[24], (const float*)d_in[25],
        out);
}